// Round 1
// baseline (1597.114 us; speedup 1.0000x reference)
//
#include <hip/hip_runtime.h>
#include <hip/hip_bf16.h>
#include <cstdint>
#include <cstddef>

#define TT 2048      // tokens (b*t)
#define DD 1024      // d
#define HH 2048      // h
#define NE 16        // experts
#define BM 64
#define BN 64
#define BK 32
#define BKP 40       // padded K extent in LDS rows (80B row stride, 16B-multiple)

typedef __bf16 bf16x8 __attribute__((ext_vector_type(8)));
typedef float f32x4 __attribute__((ext_vector_type(4)));

__device__ __forceinline__ unsigned short f2bf(float f) {
  union { float f; unsigned u; } v; v.f = f;
  unsigned r = (v.u + 0x7FFFu + ((v.u >> 16) & 1u)) >> 16;  // RNE
  return (unsigned short)r;
}
__device__ __forceinline__ float bf2f(unsigned short s) {
  union { unsigned u; float f; } v; v.u = ((unsigned)s) << 16;
  return v.f;
}

// ---------------- kernel 1: router + top-2 + bucketing ----------------
__global__ __launch_bounds__(256) void k_router(
    const float* __restrict__ x, const float* __restrict__ rw,
    const float* __restrict__ rb, int* __restrict__ cnt,
    int* __restrict__ list_tok, int* __restrict__ rec,
    float* __restrict__ wrec) {
  const int t = blockIdx.x;
  __shared__ float xs[DD];
  __shared__ float part[256];
  __shared__ float sc[NE];
  const float* xr = x + (size_t)t * DD;
  for (int i = threadIdx.x; i < DD; i += 256) xs[i] = xr[i];
  __syncthreads();
  const int e = threadIdx.x >> 4, j = threadIdx.x & 15;
  const float* w = rw + (size_t)e * DD;
  float s = 0.f;
  for (int i = j; i < DD; i += 16) s += xs[i] * w[i];
  part[threadIdx.x] = s;
  __syncthreads();
  if (threadIdx.x < NE) {
    float v = rb[threadIdx.x];
    #pragma unroll
    for (int q = 0; q < 16; ++q) v += part[threadIdx.x * 16 + q];
    sc[threadIdx.x] = v;
  }
  __syncthreads();
  if (threadIdx.x == 0) {
    int e1 = 0; float v1 = sc[0];
    #pragma unroll
    for (int q = 1; q < NE; ++q) { if (sc[q] > v1) { v1 = sc[q]; e1 = q; } }
    int e2 = -1; float v2 = -3.4e38f;
    #pragma unroll
    for (int q = 0; q < NE; ++q) {
      if (q != e1 && sc[q] > v2) { v2 = sc[q]; e2 = q; }
    }
    float ex = expf(v2 - v1);          // <= 1
    float w1 = 1.f / (1.f + ex);
    float w2 = ex / (1.f + ex);
    int p1 = atomicAdd(&cnt[e1], 1);
    int p2 = atomicAdd(&cnt[e2], 1);
    list_tok[e1 * TT + p1] = t;
    list_tok[e2 * TT + p2] = t;
    rec[t * 4 + 0] = e1; rec[t * 4 + 1] = p1;
    rec[t * 4 + 2] = e2; rec[t * 4 + 3] = p2;
    wrec[t * 2 + 0] = w1; wrec[t * 2 + 1] = w2;
  }
}

// ---------------- kernel 2: up GEMMs (mag,freq) + activation ----------------
__global__ __launch_bounds__(256) void k_upact(
    const float* __restrict__ x, const float* __restrict__ bmag,
    const float* __restrict__ bfreq, const float* __restrict__ bphase,
    const int* __restrict__ cnt, const int* __restrict__ list_tok,
    unsigned short* __restrict__ hid) {
  const int mt = blockIdx.x, nt = blockIdx.y, e = blockIdx.z;
  const int ce = cnt[e];
  if (mt * BM >= ce) return;
  __shared__ unsigned short As[BM][BKP];
  __shared__ unsigned short Bm[BN][BKP];
  __shared__ unsigned short Bf[BN][BKP];
  __shared__ int toks[BM];
  __shared__ int s_off;
  const int tid = threadIdx.x;
  if (tid < BM) {
    int r = mt * BM + tid;
    toks[tid] = list_tok[e * TT + (r < ce ? r : ce - 1)];
  }
  if (tid == 0) {
    int a = 0;
    for (int q = 0; q < e; ++q) a += cnt[q];
    s_off = a;
  }
  const int wid = tid >> 6, lane = tid & 63;
  const int wm = (wid >> 1) * 32, wn = (wid & 1) * 32;
  const int lr = lane & 15, kg = lane >> 4;
  const f32x4 zero = {0.f, 0.f, 0.f, 0.f};
  f32x4 accM[2][2], accF[2][2];
  #pragma unroll
  for (int a = 0; a < 2; ++a)
    #pragma unroll
    for (int b = 0; b < 2; ++b) { accM[a][b] = zero; accF[a][b] = zero; }
  const size_t ebase = (size_t)e * DD * HH;
  const int n0 = nt * BN;
  __syncthreads();   // toks/s_off ready; LDS clean
  for (int k0 = 0; k0 < DD; k0 += BK) {
    // stage A: 64 rows x 32 k fp32 -> bf16, [m][k]
    #pragma unroll
    for (int s = 0; s < 2; ++s) {
      int idx = s * 256 + tid;
      int r = idx >> 3;
      int c = (idx & 7) * 4;
      float4 v = *reinterpret_cast<const float4*>(x + (size_t)toks[r] * DD + k0 + c);
      ushort4 o;
      o.x = f2bf(v.x); o.y = f2bf(v.y); o.z = f2bf(v.z); o.w = f2bf(v.w);
      *reinterpret_cast<ushort4*>(&As[r][c]) = o;
    }
    // stage Bm/Bf: 32 k-rows x 64 n fp32, transposed to [n][k] with XOR swizzle
    #pragma unroll
    for (int s = 0; s < 2; ++s) {
      int idx = s * 256 + tid;
      int kk = idx >> 4;
      int u = idx & 15;
      int nn = u * 4;
      size_t g = ebase + (size_t)(k0 + kk) * HH + (n0 + nn);
      float4 vm = *reinterpret_cast<const float4*>(bmag + g);
      float4 vf = *reinterpret_cast<const float4*>(bfreq + g);
      int kks = kk ^ ((u & 3) << 3);
      Bm[nn + 0][kks] = f2bf(vm.x);
      Bm[nn + 1][kks] = f2bf(vm.y);
      Bm[nn + 2][kks] = f2bf(vm.z);
      Bm[nn + 3][kks] = f2bf(vm.w);
      Bf[nn + 0][kks] = f2bf(vf.x);
      Bf[nn + 1][kks] = f2bf(vf.y);
      Bf[nn + 2][kks] = f2bf(vf.z);
      Bf[nn + 3][kks] = f2bf(vf.w);
    }
    __syncthreads();
    bf16x8 af[2], bmv[2], bfv[2];
    #pragma unroll
    for (int fm = 0; fm < 2; ++fm)
      af[fm] = *reinterpret_cast<const bf16x8*>(&As[wm + fm * 16 + lr][kg * 8]);
    const int kswz = (kg ^ (lr >> 2)) * 8;
    #pragma unroll
    for (int fn = 0; fn < 2; ++fn) {
      bmv[fn] = *reinterpret_cast<const bf16x8*>(&Bm[wn + fn * 16 + lr][kswz]);
      bfv[fn] = *reinterpret_cast<const bf16x8*>(&Bf[wn + fn * 16 + lr][kswz]);
    }
    #pragma unroll
    for (int fm = 0; fm < 2; ++fm)
      #pragma unroll
      for (int fn = 0; fn < 2; ++fn) {
        accM[fm][fn] = __builtin_amdgcn_mfma_f32_16x16x32_bf16(af[fm], bmv[fn], accM[fm][fn], 0, 0, 0);
        accF[fm][fn] = __builtin_amdgcn_mfma_f32_16x16x32_bf16(af[fm], bfv[fn], accF[fm][fn], 0, 0, 0);
      }
    __syncthreads();
  }
  const int off = s_off;
  #pragma unroll
  for (int fm = 0; fm < 2; ++fm) {
    #pragma unroll
    for (int fn = 0; fn < 2; ++fn) {
      const int ng = n0 + wn + fn * 16 + lr;
      const float ph = bphase[e * HH + ng] + 0.1f;
      #pragma unroll
      for (int jj = 0; jj < 4; ++jj) {
        int r = mt * BM + wm + fm * 16 + kg * 4 + jj;
        if (r < ce) {
          float mv = accM[fm][fn][jj];
          float fv = accF[fm][fn][jj];
          float sp = fmaxf(fv, 0.f) + log1pf(expf(-fabsf(fv)));  // stable softplus
          float hv = tanhf(mv) * cosf(sp + ph);
          hid[(size_t)(off + r) * HH + ng] = f2bf(hv);
        }
      }
    }
  }
}

// ---------------- kernel 3: down GEMM per expert ----------------
__global__ __launch_bounds__(256) void k_down(
    const unsigned short* __restrict__ hid, const float* __restrict__ bdown,
    const int* __restrict__ cnt, unsigned short* __restrict__ op) {
  const int mt = blockIdx.x, nt = blockIdx.y, e = blockIdx.z;
  const int ce = cnt[e];
  if (mt * BM >= ce) return;
  __shared__ unsigned short As[BM][BKP];
  __shared__ unsigned short Bd[BN][BKP];
  __shared__ int s_off;
  const int tid = threadIdx.x;
  if (tid == 0) {
    int a = 0;
    for (int q = 0; q < e; ++q) a += cnt[q];
    s_off = a;
  }
  const int wid = tid >> 6, lane = tid & 63;
  const int wm = (wid >> 1) * 32, wn = (wid & 1) * 32;
  const int lr = lane & 15, kg = lane >> 4;
  const f32x4 zero = {0.f, 0.f, 0.f, 0.f};
  f32x4 acc[2][2];
  #pragma unroll
  for (int a = 0; a < 2; ++a)
    #pragma unroll
    for (int b = 0; b < 2; ++b) acc[a][b] = zero;
  const size_t ebase = (size_t)e * HH * DD;
  const int n0 = nt * BN;
  __syncthreads();
  const int off = s_off;
  for (int k0 = 0; k0 < HH; k0 += BK) {
    // stage A (hidden rows, already bf16): [m][k]
    #pragma unroll
    for (int s = 0; s < 2; ++s) {
      int idx = s * 256 + tid;
      int r = idx >> 3;
      int c = (idx & 7) * 4;
      int rr = mt * BM + r; if (rr >= ce) rr = ce - 1;
      *reinterpret_cast<ushort4*>(&As[r][c]) =
          *reinterpret_cast<const ushort4*>(hid + (size_t)(off + rr) * HH + k0 + c);
    }
    // stage B transposed+swizzled
    #pragma unroll
    for (int s = 0; s < 2; ++s) {
      int idx = s * 256 + tid;
      int kk = idx >> 4;
      int u = idx & 15;
      int nn = u * 4;
      float4 v = *reinterpret_cast<const float4*>(bdown + ebase + (size_t)(k0 + kk) * DD + (n0 + nn));
      int kks = kk ^ ((u & 3) << 3);
      Bd[nn + 0][kks] = f2bf(v.x);
      Bd[nn + 1][kks] = f2bf(v.y);
      Bd[nn + 2][kks] = f2bf(v.z);
      Bd[nn + 3][kks] = f2bf(v.w);
    }
    __syncthreads();
    bf16x8 af[2], bv[2];
    #pragma unroll
    for (int fm = 0; fm < 2; ++fm)
      af[fm] = *reinterpret_cast<const bf16x8*>(&As[wm + fm * 16 + lr][kg * 8]);
    const int kswz = (kg ^ (lr >> 2)) * 8;
    #pragma unroll
    for (int fn = 0; fn < 2; ++fn)
      bv[fn] = *reinterpret_cast<const bf16x8*>(&Bd[wn + fn * 16 + lr][kswz]);
    #pragma unroll
    for (int fm = 0; fm < 2; ++fm)
      #pragma unroll
      for (int fn = 0; fn < 2; ++fn)
        acc[fm][fn] = __builtin_amdgcn_mfma_f32_16x16x32_bf16(af[fm], bv[fn], acc[fm][fn], 0, 0, 0);
    __syncthreads();
  }
  #pragma unroll
  for (int fm = 0; fm < 2; ++fm) {
    #pragma unroll
    for (int fn = 0; fn < 2; ++fn) {
      const int ng = n0 + wn + fn * 16 + lr;
      #pragma unroll
      for (int jj = 0; jj < 4; ++jj) {
        int r = mt * BM + wm + fm * 16 + kg * 4 + jj;
        if (r < ce)
          op[(size_t)(off + r) * DD + ng] = f2bf(acc[fm][fn][jj]);
      }
    }
  }
}

// ---------------- kernel 4: combine + RMSNorm ----------------
__global__ __launch_bounds__(256) void k_norm(
    const unsigned short* __restrict__ op, const int* __restrict__ cnt,
    const int* __restrict__ rec, const float* __restrict__ wrec,
    const float* __restrict__ nw, float* __restrict__ out) {
  const int t = blockIdx.x;
  const int tid = threadIdx.x;
  __shared__ int offs[NE];
  __shared__ float red[4];
  if (tid < NE) {
    int a = 0;
    for (int q = 0; q < tid; ++q) a += cnt[q];
    offs[tid] = a;
  }
  __syncthreads();
  const int e1 = rec[t * 4 + 0], p1 = rec[t * 4 + 1];
  const int e2 = rec[t * 4 + 2], p2 = rec[t * 4 + 3];
  const float w1 = wrec[t * 2 + 0], w2 = wrec[t * 2 + 1];
  const unsigned short* pa = op + (size_t)(offs[e1] + p1) * DD;
  const unsigned short* pb = op + (size_t)(offs[e2] + p2) * DD;
  float v[4]; float ss = 0.f;
  #pragma unroll
  for (int q = 0; q < 4; ++q) {
    int i = q * 256 + tid;
    v[q] = w1 * bf2f(pa[i]) + w2 * bf2f(pb[i]);
    ss += v[q] * v[q];
  }
  #pragma unroll
  for (int o = 32; o > 0; o >>= 1) ss += __shfl_xor(ss, o);
  if ((tid & 63) == 0) red[tid >> 6] = ss;
  __syncthreads();
  const float tot = red[0] + red[1] + red[2] + red[3];
  const float scl = rsqrtf(tot * (1.f / DD) + 1e-6f);
  #pragma unroll
  for (int q = 0; q < 4; ++q) {
    int i = q * 256 + tid;
    out[(size_t)t * DD + i] = v[q] * scl * nw[i];
  }
}

extern "C" void kernel_launch(void* const* d_in, const int* in_sizes, int n_in,
                              void* d_out, int out_size, void* d_ws, size_t ws_size,
                              hipStream_t stream) {
  const float* x      = (const float*)d_in[0];
  const float* rw     = (const float*)d_in[1];
  const float* rb     = (const float*)d_in[2];
  const float* bmag   = (const float*)d_in[3];
  const float* bfreq  = (const float*)d_in[4];
  const float* bphase = (const float*)d_in[5];
  const float* bdown  = (const float*)d_in[6];
  const float* nw     = (const float*)d_in[7];
  float* out = (float*)d_out;
  char* ws = (char*)d_ws;
  // ws layout
  int*   cnt  = (int*)(ws + 0);                       // 16 int
  int*   list = (int*)(ws + 256);                     // 16*2048 int
  int*   rec  = (int*)(ws + 256 + 131072);            // 2048*4 int
  float* wrec = (float*)(ws + 256 + 131072 + 32768);  // 2048*2 f32
  unsigned short* hid = (unsigned short*)(ws + (1 << 18));                      // 4096*2048 bf16
  unsigned short* op  = (unsigned short*)(ws + (1 << 18) + (size_t)4096 * HH * 2);  // 4096*1024 bf16

  hipMemsetAsync(cnt, 0, 64, stream);
  k_router<<<TT, 256, 0, stream>>>(x, rw, rb, cnt, list, rec, wrec);
  k_upact<<<dim3(TT / BM, HH / BN, NE), 256, 0, stream>>>(x, bmag, bfreq, bphase, cnt, list, hid);
  k_down<<<dim3(TT / BM, DD / BN, NE), 256, 0, stream>>>(hid, bdown, cnt, op);
  k_norm<<<TT, 256, 0, stream>>>(op, cnt, rec, wrec, nw, out);
}

// Round 2
// 853.499 us; speedup vs baseline: 1.8713x; 1.8713x over previous
//
#include <hip/hip_runtime.h>
#include <hip/hip_bf16.h>
#include <cstdint>
#include <cstddef>

#define TT 2048      // tokens (b*t)
#define DD 1024      // d
#define HH 2048      // h
#define NE 16        // experts
#define BKW 64       // K elems per stage step (128 B rows)

typedef __bf16 bf16x8 __attribute__((ext_vector_type(8)));
typedef float f32x4 __attribute__((ext_vector_type(4)));

__device__ __forceinline__ unsigned short f2bf(float f) {
  union { float f; unsigned u; } v; v.f = f;
  unsigned r = (v.u + 0x7FFFu + ((v.u >> 16) & 1u)) >> 16;  // RNE
  return (unsigned short)r;
}
__device__ __forceinline__ float bf2f(unsigned short s) {
  union { unsigned u; float f; } v; v.u = ((unsigned)s) << 16;
  return v.f;
}

__device__ __forceinline__ void gl_lds16(const void* g, void* l) {
  __builtin_amdgcn_global_load_lds(
      (const __attribute__((address_space(1))) unsigned int*)g,
      (__attribute__((address_space(3))) unsigned int*)l, 16, 0, 0);
}

// ---------------- x fp32 -> bf16 ----------------
__global__ __launch_bounds__(256) void k_cvt_x(const float* __restrict__ x,
                                               unsigned short* __restrict__ xbf) {
  int i = blockIdx.x * 256 + threadIdx.x;   // 8 floats per thread
  const float4* p = reinterpret_cast<const float4*>(x) + (size_t)i * 2;
  float4 a = p[0], b = p[1];
  ushort4 o0 = { f2bf(a.x), f2bf(a.y), f2bf(a.z), f2bf(a.w) };
  ushort4 o1 = { f2bf(b.x), f2bf(b.y), f2bf(b.z), f2bf(b.w) };
  reinterpret_cast<ushort4*>(xbf)[(size_t)i * 2]     = o0;
  reinterpret_cast<ushort4*>(xbf)[(size_t)i * 2 + 1] = o1;
}

// ---------------- per-expert transpose: src[R][C] fp32 -> dst[C][R] bf16 ----------------
__global__ __launch_bounds__(256) void k_trans(const float* __restrict__ src,
                                               unsigned short* __restrict__ dst,
                                               int R, int C) {
  __shared__ unsigned short st[64][68];   // stride 68: 8B-aligned ushort4, 2-way-free column reads
  const int e = blockIdx.z;
  const int c0 = blockIdx.x * 64, r0 = blockIdx.y * 64;
  const float* s = src + (size_t)e * R * C;
  unsigned short* d = dst + (size_t)e * R * C;
  const int tid = threadIdx.x;
  #pragma unroll
  for (int p = 0; p < 4; ++p) {
    int r = p * 16 + (tid >> 4);
    int c = (tid & 15) * 4;
    float4 v = *reinterpret_cast<const float4*>(s + (size_t)(r0 + r) * C + c0 + c);
    ushort4 o = { f2bf(v.x), f2bf(v.y), f2bf(v.z), f2bf(v.w) };
    *reinterpret_cast<ushort4*>(&st[r][c]) = o;
  }
  __syncthreads();
  #pragma unroll
  for (int q = 0; q < 4; ++q) {
    int c = q * 16 + (tid >> 4);
    int r4 = (tid & 15) * 4;
    ushort4 o = { st[r4][c], st[r4 + 1][c], st[r4 + 2][c], st[r4 + 3][c] };
    *reinterpret_cast<ushort4*>(d + (size_t)(c0 + c) * R + r0 + r4) = o;
  }
}

// ---------------- router + top-2 + bucketing ----------------
__global__ __launch_bounds__(256) void k_router(
    const float* __restrict__ x, const float* __restrict__ rw,
    const float* __restrict__ rb, int* __restrict__ cnt,
    int* __restrict__ list_tok, int* __restrict__ rec,
    float* __restrict__ wrec) {
  const int t = blockIdx.x;
  __shared__ float xs[DD];
  __shared__ float part[256];
  __shared__ float sc[NE];
  const float* xr = x + (size_t)t * DD;
  for (int i = threadIdx.x; i < DD; i += 256) xs[i] = xr[i];
  __syncthreads();
  const int e = threadIdx.x >> 4, j = threadIdx.x & 15;
  const float* w = rw + (size_t)e * DD;
  float s = 0.f;
  for (int i = j; i < DD; i += 16) s += xs[i] * w[i];
  part[threadIdx.x] = s;
  __syncthreads();
  if (threadIdx.x < NE) {
    float v = rb[threadIdx.x];
    #pragma unroll
    for (int q = 0; q < 16; ++q) v += part[threadIdx.x * 16 + q];
    sc[threadIdx.x] = v;
  }
  __syncthreads();
  if (threadIdx.x == 0) {
    int e1 = 0; float v1 = sc[0];
    #pragma unroll
    for (int q = 1; q < NE; ++q) { if (sc[q] > v1) { v1 = sc[q]; e1 = q; } }
    int e2 = -1; float v2 = -3.4e38f;
    #pragma unroll
    for (int q = 0; q < NE; ++q) {
      if (q != e1 && sc[q] > v2) { v2 = sc[q]; e2 = q; }
    }
    float ex = expf(v2 - v1);          // <= 1
    float w1 = 1.f / (1.f + ex);
    float w2 = ex / (1.f + ex);
    int p1 = atomicAdd(&cnt[e1], 1);
    int p2 = atomicAdd(&cnt[e2], 1);
    list_tok[e1 * TT + p1] = t;
    list_tok[e2 * TT + p2] = t;
    rec[t * 4 + 0] = e1; rec[t * 4 + 1] = p1;
    rec[t * 4 + 2] = e2; rec[t * 4 + 3] = p2;
    wrec[t * 2 + 0] = w1; wrec[t * 2 + 1] = w2;
  }
}

// ---------------- up GEMMs (mag,freq) + activation ----------------
// BM=128, BN=64, BK=64, 256 thr (4 waves 2x2), per-wave 64x32, double-buffered,
// global_load_lds staging with XOR chunk swizzle (chunk ^= row&7 on source & read).
__global__ __launch_bounds__(256, 2) void k_up(
    const unsigned short* __restrict__ xbf,
    const unsigned short* __restrict__ wmT,   // [e][HH][DD] bf16
    const unsigned short* __restrict__ wfT,   // [e][HH][DD] bf16
    const float* __restrict__ bphase,
    const int* __restrict__ cnt, const int* __restrict__ list_tok,
    unsigned short* __restrict__ hid) {
  const int mt = blockIdx.x, nt = blockIdx.y, e = blockIdx.z;
  const int ce = cnt[e];
  if (mt * 128 >= ce) return;
  __shared__ unsigned short As[2][128][BKW];
  __shared__ unsigned short Bm[2][64][BKW];
  __shared__ unsigned short Bf[2][64][BKW];
  __shared__ int toks[128];
  __shared__ int s_off;
  const int tid = threadIdx.x;
  if (tid < 128) {
    int r = mt * 128 + tid;
    toks[tid] = list_tok[e * TT + (r < ce ? r : ce - 1)];
  }
  if (tid == 0) {
    int a = 0;
    for (int q = 0; q < e; ++q) a += cnt[q];
    s_off = a;
  }
  __syncthreads();
  const int w = tid >> 6, l = tid & 63;
  const int lhi = l >> 3, llo = l & 7;
  // staging bases (ushort offsets into global), LDS ushort offsets (linear per lane)
  size_t abase[4]; int aoff[4];
  #pragma unroll
  for (int j = 0; j < 4; ++j) {
    int seg = w * 4 + j;
    int r = seg * 8 + lhi;
    abase[j] = (size_t)toks[r] * DD + (size_t)(((llo ^ (r & 7)) * 8));
    aoff[j] = seg * 512 + l * 8;
  }
  size_t bbase[4]; int boff[4];   // j0..1 -> Bm segs, j2..3 -> Bf segs
  #pragma unroll
  for (int j = 0; j < 4; ++j) {
    int seg = w * 2 + (j & 1);
    int n = seg * 8 + lhi;
    bbase[j] = ((size_t)e * HH + nt * 64 + n) * DD + (size_t)(((llo ^ (n & 7)) * 8));
    boff[j] = seg * 512 + l * 8;
  }
  const int wm = (w >> 1) * 64, wn = (w & 1) * 32;
  const int lr = l & 15, kg = l >> 4;
  const f32x4 zero = {0.f, 0.f, 0.f, 0.f};
  f32x4 accM[4][2], accF[4][2];
  #pragma unroll
  for (int a = 0; a < 4; ++a)
    #pragma unroll
    for (int b = 0; b < 2; ++b) { accM[a][b] = zero; accF[a][b] = zero; }

  auto stage = [&](int buf, int kt) {
    const int ko = kt * BKW;
    unsigned short* As_b = &As[buf][0][0];
    unsigned short* Bm_b = &Bm[buf][0][0];
    unsigned short* Bf_b = &Bf[buf][0][0];
    #pragma unroll
    for (int j = 0; j < 4; ++j) gl_lds16(xbf + abase[j] + ko, As_b + aoff[j]);
    gl_lds16(wmT + bbase[0] + ko, Bm_b + boff[0]);
    gl_lds16(wmT + bbase[1] + ko, Bm_b + boff[1]);
    gl_lds16(wfT + bbase[2] + ko, Bf_b + boff[2]);
    gl_lds16(wfT + bbase[3] + ko, Bf_b + boff[3]);
  };

  stage(0, 0);
  __syncthreads();
  int buf = 0;
  for (int kt = 0; kt < DD / BKW; ++kt) {
    if (kt + 1 < DD / BKW) stage(buf ^ 1, kt + 1);
    #pragma unroll
    for (int ks = 0; ks < 2; ++ks) {
      const int csw = ((ks * 4 + kg) ^ (lr & 7)) * 8;
      bf16x8 av[4], bmv[2], bfv[2];
      #pragma unroll
      for (int fm = 0; fm < 4; ++fm)
        av[fm] = *reinterpret_cast<const bf16x8*>(&As[buf][wm + fm * 16 + lr][0] + csw);
      #pragma unroll
      for (int fn = 0; fn < 2; ++fn) {
        bmv[fn] = *reinterpret_cast<const bf16x8*>(&Bm[buf][wn + fn * 16 + lr][0] + csw);
        bfv[fn] = *reinterpret_cast<const bf16x8*>(&Bf[buf][wn + fn * 16 + lr][0] + csw);
      }
      #pragma unroll
      for (int fm = 0; fm < 4; ++fm)
        #pragma unroll
        for (int fn = 0; fn < 2; ++fn) {
          accM[fm][fn] = __builtin_amdgcn_mfma_f32_16x16x32_bf16(av[fm], bmv[fn], accM[fm][fn], 0, 0, 0);
          accF[fm][fn] = __builtin_amdgcn_mfma_f32_16x16x32_bf16(av[fm], bfv[fn], accF[fm][fn], 0, 0, 0);
        }
    }
    __syncthreads();
    buf ^= 1;
  }
  const int off = s_off;
  #pragma unroll
  for (int fn = 0; fn < 2; ++fn) {
    const int ng = nt * 64 + wn + fn * 16 + lr;
    const float ph = bphase[e * HH + ng] + 0.1f;
    #pragma unroll
    for (int fm = 0; fm < 4; ++fm) {
      #pragma unroll
      for (int jj = 0; jj < 4; ++jj) {
        int m = mt * 128 + wm + fm * 16 + kg * 4 + jj;
        if (m < ce) {
          float mv = accM[fm][fn][jj];
          float fv = accF[fm][fn][jj];
          float exn = __expf(-fabsf(fv));
          float sp = fmaxf(fv, 0.f) + __logf(1.f + exn);   // stable softplus
          float t2 = __expf(2.f * mv);
          float th = 1.f - 2.f / (t2 + 1.f);               // tanh
          float hv = th * __cosf(sp + ph);
          hid[(size_t)(off + m) * HH + ng] = f2bf(hv);
        }
      }
    }
  }
}

// ---------------- down GEMM ----------------
__global__ __launch_bounds__(256, 2) void k_down(
    const unsigned short* __restrict__ hid,
    const unsigned short* __restrict__ wdT,   // [e][DD][HH] bf16
    const int* __restrict__ cnt,
    unsigned short* __restrict__ op) {
  const int mt = blockIdx.x, nt = blockIdx.y, e = blockIdx.z;
  const int ce = cnt[e];
  if (mt * 128 >= ce) return;
  __shared__ unsigned short As[2][128][BKW];
  __shared__ unsigned short Bd[2][64][BKW];
  __shared__ int s_off;
  const int tid = threadIdx.x;
  if (tid == 0) {
    int a = 0;
    for (int q = 0; q < e; ++q) a += cnt[q];
    s_off = a;
  }
  __syncthreads();
  const int off = s_off;
  const int w = tid >> 6, l = tid & 63;
  const int lhi = l >> 3, llo = l & 7;
  size_t abase[4]; int aoff[4];
  #pragma unroll
  for (int j = 0; j < 4; ++j) {
    int seg = w * 4 + j;
    int r = seg * 8 + lhi;
    int gr = mt * 128 + r; if (gr >= ce) gr = ce - 1;
    abase[j] = (size_t)(off + gr) * HH + (size_t)(((llo ^ (r & 7)) * 8));
    aoff[j] = seg * 512 + l * 8;
  }
  size_t bbase[2]; int boff[2];
  #pragma unroll
  for (int j = 0; j < 2; ++j) {
    int seg = w * 2 + j;
    int n = seg * 8 + lhi;
    bbase[j] = ((size_t)e * DD + nt * 64 + n) * HH + (size_t)(((llo ^ (n & 7)) * 8));
    boff[j] = seg * 512 + l * 8;
  }
  const int wm = (w >> 1) * 64, wn = (w & 1) * 32;
  const int lr = l & 15, kg = l >> 4;
  const f32x4 zero = {0.f, 0.f, 0.f, 0.f};
  f32x4 acc[4][2];
  #pragma unroll
  for (int a = 0; a < 4; ++a)
    #pragma unroll
    for (int b = 0; b < 2; ++b) acc[a][b] = zero;

  auto stage = [&](int buf, int kt) {
    const int ko = kt * BKW;
    unsigned short* As_b = &As[buf][0][0];
    unsigned short* Bd_b = &Bd[buf][0][0];
    #pragma unroll
    for (int j = 0; j < 4; ++j) gl_lds16(hid + abase[j] + ko, As_b + aoff[j]);
    #pragma unroll
    for (int j = 0; j < 2; ++j) gl_lds16(wdT + bbase[j] + ko, Bd_b + boff[j]);
  };

  stage(0, 0);
  __syncthreads();
  int buf = 0;
  for (int kt = 0; kt < HH / BKW; ++kt) {
    if (kt + 1 < HH / BKW) stage(buf ^ 1, kt + 1);
    #pragma unroll
    for (int ks = 0; ks < 2; ++ks) {
      const int csw = ((ks * 4 + kg) ^ (lr & 7)) * 8;
      bf16x8 av[4], bv[2];
      #pragma unroll
      for (int fm = 0; fm < 4; ++fm)
        av[fm] = *reinterpret_cast<const bf16x8*>(&As[buf][wm + fm * 16 + lr][0] + csw);
      #pragma unroll
      for (int fn = 0; fn < 2; ++fn)
        bv[fn] = *reinterpret_cast<const bf16x8*>(&Bd[buf][wn + fn * 16 + lr][0] + csw);
      #pragma unroll
      for (int fm = 0; fm < 4; ++fm)
        #pragma unroll
        for (int fn = 0; fn < 2; ++fn)
          acc[fm][fn] = __builtin_amdgcn_mfma_f32_16x16x32_bf16(av[fm], bv[fn], acc[fm][fn], 0, 0, 0);
    }
    __syncthreads();
    buf ^= 1;
  }
  #pragma unroll
  for (int fn = 0; fn < 2; ++fn) {
    const int ng = nt * 64 + wn + fn * 16 + lr;
    #pragma unroll
    for (int fm = 0; fm < 4; ++fm) {
      #pragma unroll
      for (int jj = 0; jj < 4; ++jj) {
        int m = mt * 128 + wm + fm * 16 + kg * 4 + jj;
        if (m < ce)
          op[(size_t)(off + m) * DD + ng] = f2bf(acc[fm][fn][jj]);
      }
    }
  }
}

// ---------------- combine + RMSNorm ----------------
__global__ __launch_bounds__(256) void k_norm(
    const unsigned short* __restrict__ op, const int* __restrict__ cnt,
    const int* __restrict__ rec, const float* __restrict__ wrec,
    const float* __restrict__ nw, float* __restrict__ out) {
  const int t = blockIdx.x;
  const int tid = threadIdx.x;
  __shared__ int offs[NE];
  __shared__ float red[4];
  if (tid < NE) {
    int a = 0;
    for (int q = 0; q < tid; ++q) a += cnt[q];
    offs[tid] = a;
  }
  __syncthreads();
  const int e1 = rec[t * 4 + 0], p1 = rec[t * 4 + 1];
  const int e2 = rec[t * 4 + 2], p2 = rec[t * 4 + 3];
  const float w1 = wrec[t * 2 + 0], w2 = wrec[t * 2 + 1];
  const unsigned short* pa = op + (size_t)(offs[e1] + p1) * DD;
  const unsigned short* pb = op + (size_t)(offs[e2] + p2) * DD;
  float v[4]; float ss = 0.f;
  #pragma unroll
  for (int q = 0; q < 4; ++q) {
    int i = q * 256 + tid;
    v[q] = w1 * bf2f(pa[i]) + w2 * bf2f(pb[i]);
    ss += v[q] * v[q];
  }
  #pragma unroll
  for (int o = 32; o > 0; o >>= 1) ss += __shfl_xor(ss, o);
  if ((tid & 63) == 0) red[tid >> 6] = ss;
  __syncthreads();
  const float tot = red[0] + red[1] + red[2] + red[3];
  const float scl = rsqrtf(tot * (1.f / DD) + 1e-6f);
  #pragma unroll
  for (int q = 0; q < 4; ++q) {
    int i = q * 256 + tid;
    out[(size_t)t * DD + i] = v[q] * scl * nw[i];
  }
}

extern "C" void kernel_launch(void* const* d_in, const int* in_sizes, int n_in,
                              void* d_out, int out_size, void* d_ws, size_t ws_size,
                              hipStream_t stream) {
  const float* x      = (const float*)d_in[0];
  const float* rw     = (const float*)d_in[1];
  const float* rb     = (const float*)d_in[2];
  const float* bmag   = (const float*)d_in[3];
  const float* bfreq  = (const float*)d_in[4];
  const float* bphase = (const float*)d_in[5];
  const float* bdown  = (const float*)d_in[6];
  const float* nw     = (const float*)d_in[7];
  float* out = (float*)d_out;
  char* ws = (char*)d_ws;
  const size_t MB = 1024 * 1024;
  // ws layout
  int*   cnt  = (int*)(ws + 0);                    // 16 int
  int*   list = (int*)(ws + 256);                  // 16*2048 int
  int*   rec  = (int*)(ws + 256 + 131072);         // 2048*4 int
  float* wrec = (float*)(ws + 256 + 131072 + 32768);
  unsigned short* xbf = (unsigned short*)(ws + 1 * MB);    // 4 MB
  unsigned short* hid = (unsigned short*)(ws + 5 * MB);    // 16 MB
  unsigned short* op  = (unsigned short*)(ws + 21 * MB);   // 8 MB
  unsigned short* wmT = (unsigned short*)(ws + 32 * MB);   // 64 MB (reused by wdT)
  unsigned short* wfT = (unsigned short*)(ws + 96 * MB);   // 64 MB
  unsigned short* wdT = wmT;                               // alias: used after k_up

  hipMemsetAsync(cnt, 0, 64, stream);
  k_cvt_x<<<1024, 256, 0, stream>>>(x, xbf);
  k_router<<<TT, 256, 0, stream>>>(x, rw, rb, cnt, list, rec, wrec);
  k_trans<<<dim3(HH / 64, DD / 64, NE), 256, 0, stream>>>(bmag, wmT, DD, HH);
  k_trans<<<dim3(HH / 64, DD / 64, NE), 256, 0, stream>>>(bfreq, wfT, DD, HH);
  k_up<<<dim3(TT / 128, HH / 64, NE), 256, 0, stream>>>(xbf, wmT, wfT, bphase, cnt, list, hid);
  k_trans<<<dim3(DD / 64, HH / 64, NE), 256, 0, stream>>>(bdown, wdT, HH, DD);
  k_down<<<dim3(TT / 128, DD / 64, NE), 256, 0, stream>>>(hid, wdT, cnt, op);
  k_norm<<<TT, 256, 0, stream>>>(op, cnt, rec, wrec, nw, out);
}

// Round 3
// 334.306 us; speedup vs baseline: 4.7774x; 2.5530x over previous
//
#include <hip/hip_runtime.h>
#include <hip/hip_bf16.h>
#include <cstdint>
#include <cstddef>

#define TT 2048      // tokens (b*t)
#define DD 1024      // d
#define HH 2048      // h
#define NE 16        // experts
#define BKW 64       // K elems per stage step (128 B rows)
#define WMAX 48      // max (expert, m-block) work items: sum ceil(ce/128) <= 4096/128 + 16

typedef __bf16 bf16x8 __attribute__((ext_vector_type(8)));
typedef float f32x4 __attribute__((ext_vector_type(4)));

__device__ __forceinline__ unsigned short f2bf(float f) {
  union { float f; unsigned u; } v; v.f = f;
  unsigned r = (v.u + 0x7FFFu + ((v.u >> 16) & 1u)) >> 16;  // RNE
  return (unsigned short)r;
}
__device__ __forceinline__ float bf2f(unsigned short s) {
  union { unsigned u; float f; } v; v.u = ((unsigned)s) << 16;
  return v.f;
}

__device__ __forceinline__ void gl_lds16(const void* g, void* l) {
  __builtin_amdgcn_global_load_lds(
      (const __attribute__((address_space(1))) unsigned int*)g,
      (__attribute__((address_space(3))) unsigned int*)l, 16, 0, 0);
}

// ---------------- x fp32 -> bf16 ----------------
__global__ __launch_bounds__(256) void k_cvt_x(const float* __restrict__ x,
                                               unsigned short* __restrict__ xbf) {
  int i = blockIdx.x * 256 + threadIdx.x;   // 8 floats per thread
  const float4* p = reinterpret_cast<const float4*>(x) + (size_t)i * 2;
  float4 a = p[0], b = p[1];
  ushort4 o0 = { f2bf(a.x), f2bf(a.y), f2bf(a.z), f2bf(a.w) };
  ushort4 o1 = { f2bf(b.x), f2bf(b.y), f2bf(b.z), f2bf(b.w) };
  reinterpret_cast<ushort4*>(xbf)[(size_t)i * 2]     = o0;
  reinterpret_cast<ushort4*>(xbf)[(size_t)i * 2 + 1] = o1;
}

// ---------------- per-expert transpose: src[R][C] fp32 -> dst[C][R] bf16 ----------------
__global__ __launch_bounds__(256) void k_trans(const float* __restrict__ src,
                                               unsigned short* __restrict__ dst,
                                               int R, int C) {
  __shared__ unsigned short st[64][68];
  const int e = blockIdx.z;
  const int c0 = blockIdx.x * 64, r0 = blockIdx.y * 64;
  const float* s = src + (size_t)e * R * C;
  unsigned short* d = dst + (size_t)e * R * C;
  const int tid = threadIdx.x;
  #pragma unroll
  for (int p = 0; p < 4; ++p) {
    int r = p * 16 + (tid >> 4);
    int c = (tid & 15) * 4;
    float4 v = *reinterpret_cast<const float4*>(s + (size_t)(r0 + r) * C + c0 + c);
    ushort4 o = { f2bf(v.x), f2bf(v.y), f2bf(v.z), f2bf(v.w) };
    *reinterpret_cast<ushort4*>(&st[r][c]) = o;
  }
  __syncthreads();
  #pragma unroll
  for (int q = 0; q < 4; ++q) {
    int c = q * 16 + (tid >> 4);
    int r4 = (tid & 15) * 4;
    ushort4 o = { st[r4][c], st[r4 + 1][c], st[r4 + 2][c], st[r4 + 3][c] };
    *reinterpret_cast<ushort4*>(d + (size_t)(c0 + c) * R + r0 + r4) = o;
  }
}

// ---------------- router + top-2 + bucketing ----------------
__global__ __launch_bounds__(256) void k_router(
    const float* __restrict__ x, const float* __restrict__ rw,
    const float* __restrict__ rb, int* __restrict__ cnt,
    int* __restrict__ list_tok, int* __restrict__ rec,
    float* __restrict__ wrec) {
  const int t = blockIdx.x;
  __shared__ float xs[DD];
  __shared__ float part[256];
  __shared__ float sc[NE];
  const float* xr = x + (size_t)t * DD;
  for (int i = threadIdx.x; i < DD; i += 256) xs[i] = xr[i];
  __syncthreads();
  const int e = threadIdx.x >> 4, j = threadIdx.x & 15;
  const float* w = rw + (size_t)e * DD;
  float s = 0.f;
  for (int i = j; i < DD; i += 16) s += xs[i] * w[i];
  part[threadIdx.x] = s;
  __syncthreads();
  if (threadIdx.x < NE) {
    float v = rb[threadIdx.x];
    #pragma unroll
    for (int q = 0; q < 16; ++q) v += part[threadIdx.x * 16 + q];
    sc[threadIdx.x] = v;
  }
  __syncthreads();
  if (threadIdx.x == 0) {
    int e1 = 0; float v1 = sc[0];
    #pragma unroll
    for (int q = 1; q < NE; ++q) { if (sc[q] > v1) { v1 = sc[q]; e1 = q; } }
    int e2 = -1; float v2 = -3.4e38f;
    #pragma unroll
    for (int q = 0; q < NE; ++q) {
      if (q != e1 && sc[q] > v2) { v2 = sc[q]; e2 = q; }
    }
    float ex = expf(v2 - v1);          // <= 1
    float w1 = 1.f / (1.f + ex);
    float w2 = ex / (1.f + ex);
    int p1 = atomicAdd(&cnt[e1], 1);
    int p2 = atomicAdd(&cnt[e2], 1);
    list_tok[e1 * TT + p1] = t;
    list_tok[e2 * TT + p2] = t;
    rec[t * 4 + 0] = e1; rec[t * 4 + 1] = p1;
    rec[t * 4 + 2] = e2; rec[t * 4 + 3] = p2;
    wrec[t * 2 + 0] = w1; wrec[t * 2 + 1] = w2;
  }
}

// ---------------- work-table builder: dense (expert, m-block) list ----------------
__global__ void k_sched(const int* __restrict__ cnt, int* __restrict__ work,
                        int* __restrict__ woff) {
  if (threadIdx.x == 0) {
    int o = 0, nw = 0;
    for (int e = 0; e < NE; ++e) {
      int ce = cnt[e];
      int nmb = (ce + 127) >> 7;
      for (int mb = 0; mb < nmb; ++mb) {
        work[nw * 2 + 0] = e; work[nw * 2 + 1] = mb; ++nw;
      }
      woff[e] = o; o += ce;
    }
    for (int q = nw; q < WMAX; ++q) { work[q * 2 + 0] = -1; work[q * 2 + 1] = 0; }
  }
}

// ---------------- up GEMMs (mag,freq) + activation ----------------
// BM=128, BN=64, BK=64, 256 thr (4 waves 2x2), per-wave 64x32, double-buffered,
// global_load_lds staging with XOR chunk swizzle on source & read.
__global__ __launch_bounds__(256, 2) void k_up(
    const unsigned short* __restrict__ xbf,
    const unsigned short* __restrict__ wmT,   // [e][HH][DD] bf16
    const unsigned short* __restrict__ wfT,   // [e][HH][DD] bf16
    const float* __restrict__ bphase,
    const int* __restrict__ cnt, const int* __restrict__ list_tok,
    const int* __restrict__ work, const int* __restrict__ woff,
    unsigned short* __restrict__ hid) {
  const int e = work[blockIdx.x * 2 + 0];
  if (e < 0) return;
  const int mt = work[blockIdx.x * 2 + 1];
  const int nt = blockIdx.y;
  const int ce = cnt[e];
  const int off = woff[e];
  __shared__ unsigned short As[2][128][BKW];
  __shared__ unsigned short Bm[2][64][BKW];
  __shared__ unsigned short Bf[2][64][BKW];
  __shared__ int toks[128];
  const int tid = threadIdx.x;
  if (tid < 128) {
    int r = mt * 128 + tid;
    toks[tid] = list_tok[e * TT + (r < ce ? r : ce - 1)];
  }
  __syncthreads();
  const int w = tid >> 6, l = tid & 63;
  const int lhi = l >> 3, llo = l & 7;
  size_t abase[4]; int aoff[4];
  #pragma unroll
  for (int j = 0; j < 4; ++j) {
    int seg = w * 4 + j;
    int r = seg * 8 + lhi;
    abase[j] = (size_t)toks[r] * DD + (size_t)(((llo ^ (r & 7)) * 8));
    aoff[j] = seg * 512 + l * 8;
  }
  size_t bbase[4]; int boff[4];   // j0..1 -> Bm segs, j2..3 -> Bf segs
  #pragma unroll
  for (int j = 0; j < 4; ++j) {
    int seg = w * 2 + (j & 1);
    int n = seg * 8 + lhi;
    bbase[j] = ((size_t)e * HH + nt * 64 + n) * DD + (size_t)(((llo ^ (n & 7)) * 8));
    boff[j] = seg * 512 + l * 8;
  }
  const int wm = (w >> 1) * 64, wn = (w & 1) * 32;
  const int lr = l & 15, kg = l >> 4;
  const f32x4 zero = {0.f, 0.f, 0.f, 0.f};
  f32x4 accM[4][2], accF[4][2];
  #pragma unroll
  for (int a = 0; a < 4; ++a)
    #pragma unroll
    for (int b = 0; b < 2; ++b) { accM[a][b] = zero; accF[a][b] = zero; }

  auto stage = [&](int buf, int kt) {
    const int ko = kt * BKW;
    unsigned short* As_b = &As[buf][0][0];
    unsigned short* Bm_b = &Bm[buf][0][0];
    unsigned short* Bf_b = &Bf[buf][0][0];
    #pragma unroll
    for (int j = 0; j < 4; ++j) gl_lds16(xbf + abase[j] + ko, As_b + aoff[j]);
    gl_lds16(wmT + bbase[0] + ko, Bm_b + boff[0]);
    gl_lds16(wmT + bbase[1] + ko, Bm_b + boff[1]);
    gl_lds16(wfT + bbase[2] + ko, Bf_b + boff[2]);
    gl_lds16(wfT + bbase[3] + ko, Bf_b + boff[3]);
  };

  stage(0, 0);
  __syncthreads();
  int buf = 0;
  for (int kt = 0; kt < DD / BKW; ++kt) {
    if (kt + 1 < DD / BKW) stage(buf ^ 1, kt + 1);
    #pragma unroll
    for (int ks = 0; ks < 2; ++ks) {
      const int csw = ((ks * 4 + kg) ^ (lr & 7)) * 8;
      bf16x8 av[4], bmv[2], bfv[2];
      #pragma unroll
      for (int fm = 0; fm < 4; ++fm)
        av[fm] = *reinterpret_cast<const bf16x8*>(&As[buf][wm + fm * 16 + lr][0] + csw);
      #pragma unroll
      for (int fn = 0; fn < 2; ++fn) {
        bmv[fn] = *reinterpret_cast<const bf16x8*>(&Bm[buf][wn + fn * 16 + lr][0] + csw);
        bfv[fn] = *reinterpret_cast<const bf16x8*>(&Bf[buf][wn + fn * 16 + lr][0] + csw);
      }
      #pragma unroll
      for (int fm = 0; fm < 4; ++fm)
        #pragma unroll
        for (int fn = 0; fn < 2; ++fn) {
          accM[fm][fn] = __builtin_amdgcn_mfma_f32_16x16x32_bf16(av[fm], bmv[fn], accM[fm][fn], 0, 0, 0);
          accF[fm][fn] = __builtin_amdgcn_mfma_f32_16x16x32_bf16(av[fm], bfv[fn], accF[fm][fn], 0, 0, 0);
        }
    }
    __syncthreads();
    buf ^= 1;
  }
  #pragma unroll
  for (int fn = 0; fn < 2; ++fn) {
    const int ng = nt * 64 + wn + fn * 16 + lr;
    const float ph = bphase[e * HH + ng] + 0.1f;
    #pragma unroll
    for (int fm = 0; fm < 4; ++fm) {
      #pragma unroll
      for (int jj = 0; jj < 4; ++jj) {
        int m = mt * 128 + wm + fm * 16 + kg * 4 + jj;
        if (m < ce) {
          float mv = accM[fm][fn][jj];
          float fv = accF[fm][fn][jj];
          float exn = __expf(-fabsf(fv));
          float sp = fmaxf(fv, 0.f) + __logf(1.f + exn);   // stable softplus
          float t2 = __expf(2.f * mv);
          float th = 1.f - 2.f / (t2 + 1.f);               // tanh
          float hv = th * __cosf(sp + ph);
          hid[(size_t)(off + m) * HH + ng] = f2bf(hv);
        }
      }
    }
  }
}

// ---------------- down GEMM ----------------
__global__ __launch_bounds__(256, 2) void k_down(
    const unsigned short* __restrict__ hid,
    const unsigned short* __restrict__ wdT,   // [e][DD][HH] bf16
    const int* __restrict__ cnt,
    const int* __restrict__ work, const int* __restrict__ woff,
    unsigned short* __restrict__ op) {
  const int e = work[blockIdx.x * 2 + 0];
  if (e < 0) return;
  const int mt = work[blockIdx.x * 2 + 1];
  const int nt = blockIdx.y;
  const int ce = cnt[e];
  const int off = woff[e];
  __shared__ unsigned short As[2][128][BKW];
  __shared__ unsigned short Bd[2][64][BKW];
  const int tid = threadIdx.x;
  const int w = tid >> 6, l = tid & 63;
  const int lhi = l >> 3, llo = l & 7;
  size_t abase[4]; int aoff[4];
  #pragma unroll
  for (int j = 0; j < 4; ++j) {
    int seg = w * 4 + j;
    int r = seg * 8 + lhi;
    int gr = mt * 128 + r; if (gr >= ce) gr = ce - 1;
    abase[j] = (size_t)(off + gr) * HH + (size_t)(((llo ^ (r & 7)) * 8));
    aoff[j] = seg * 512 + l * 8;
  }
  size_t bbase[2]; int boff[2];
  #pragma unroll
  for (int j = 0; j < 2; ++j) {
    int seg = w * 2 + j;
    int n = seg * 8 + lhi;
    bbase[j] = ((size_t)e * DD + nt * 64 + n) * HH + (size_t)(((llo ^ (n & 7)) * 8));
    boff[j] = seg * 512 + l * 8;
  }
  const int wm = (w >> 1) * 64, wn = (w & 1) * 32;
  const int lr = l & 15, kg = l >> 4;
  const f32x4 zero = {0.f, 0.f, 0.f, 0.f};
  f32x4 acc[4][2];
  #pragma unroll
  for (int a = 0; a < 4; ++a)
    #pragma unroll
    for (int b = 0; b < 2; ++b) acc[a][b] = zero;

  auto stage = [&](int buf, int kt) {
    const int ko = kt * BKW;
    unsigned short* As_b = &As[buf][0][0];
    unsigned short* Bd_b = &Bd[buf][0][0];
    #pragma unroll
    for (int j = 0; j < 4; ++j) gl_lds16(hid + abase[j] + ko, As_b + aoff[j]);
    #pragma unroll
    for (int j = 0; j < 2; ++j) gl_lds16(wdT + bbase[j] + ko, Bd_b + boff[j]);
  };

  stage(0, 0);
  __syncthreads();
  int buf = 0;
  for (int kt = 0; kt < HH / BKW; ++kt) {
    if (kt + 1 < HH / BKW) stage(buf ^ 1, kt + 1);
    #pragma unroll
    for (int ks = 0; ks < 2; ++ks) {
      const int csw = ((ks * 4 + kg) ^ (lr & 7)) * 8;
      bf16x8 av[4], bv[2];
      #pragma unroll
      for (int fm = 0; fm < 4; ++fm)
        av[fm] = *reinterpret_cast<const bf16x8*>(&As[buf][wm + fm * 16 + lr][0] + csw);
      #pragma unroll
      for (int fn = 0; fn < 2; ++fn)
        bv[fn] = *reinterpret_cast<const bf16x8*>(&Bd[buf][wn + fn * 16 + lr][0] + csw);
      #pragma unroll
      for (int fm = 0; fm < 4; ++fm)
        #pragma unroll
        for (int fn = 0; fn < 2; ++fn)
          acc[fm][fn] = __builtin_amdgcn_mfma_f32_16x16x32_bf16(av[fm], bv[fn], acc[fm][fn], 0, 0, 0);
    }
    __syncthreads();
    buf ^= 1;
  }
  #pragma unroll
  for (int fn = 0; fn < 2; ++fn) {
    const int ng = nt * 64 + wn + fn * 16 + lr;
    #pragma unroll
    for (int fm = 0; fm < 4; ++fm) {
      #pragma unroll
      for (int jj = 0; jj < 4; ++jj) {
        int m = mt * 128 + wm + fm * 16 + kg * 4 + jj;
        if (m < ce)
          op[(size_t)(off + m) * DD + ng] = f2bf(acc[fm][fn][jj]);
      }
    }
  }
}

// ---------------- combine + RMSNorm ----------------
__global__ __launch_bounds__(256) void k_norm(
    const unsigned short* __restrict__ op, const int* __restrict__ woff,
    const int* __restrict__ rec, const float* __restrict__ wrec,
    const float* __restrict__ nw, float* __restrict__ out) {
  const int t = blockIdx.x;
  const int tid = threadIdx.x;
  __shared__ float red[4];
  const int e1 = rec[t * 4 + 0], p1 = rec[t * 4 + 1];
  const int e2 = rec[t * 4 + 2], p2 = rec[t * 4 + 3];
  const float w1 = wrec[t * 2 + 0], w2 = wrec[t * 2 + 1];
  const unsigned short* pa = op + (size_t)(woff[e1] + p1) * DD;
  const unsigned short* pb = op + (size_t)(woff[e2] + p2) * DD;
  float v[4]; float ss = 0.f;
  #pragma unroll
  for (int q = 0; q < 4; ++q) {
    int i = q * 256 + tid;
    v[q] = w1 * bf2f(pa[i]) + w2 * bf2f(pb[i]);
    ss += v[q] * v[q];
  }
  #pragma unroll
  for (int o = 32; o > 0; o >>= 1) ss += __shfl_xor(ss, o);
  if ((tid & 63) == 0) red[tid >> 6] = ss;
  __syncthreads();
  const float tot = red[0] + red[1] + red[2] + red[3];
  const float scl = rsqrtf(tot * (1.f / DD) + 1e-6f);
  #pragma unroll
  for (int q = 0; q < 4; ++q) {
    int i = q * 256 + tid;
    out[(size_t)t * DD + i] = v[q] * scl * nw[i];
  }
}

extern "C" void kernel_launch(void* const* d_in, const int* in_sizes, int n_in,
                              void* d_out, int out_size, void* d_ws, size_t ws_size,
                              hipStream_t stream) {
  const float* x      = (const float*)d_in[0];
  const float* rw     = (const float*)d_in[1];
  const float* rb     = (const float*)d_in[2];
  const float* bmag   = (const float*)d_in[3];
  const float* bfreq  = (const float*)d_in[4];
  const float* bphase = (const float*)d_in[5];
  const float* bdown  = (const float*)d_in[6];
  const float* nw     = (const float*)d_in[7];
  float* out = (float*)d_out;
  char* ws = (char*)d_ws;
  const size_t MB = 1024 * 1024;
  // ws layout
  int*   cnt  = (int*)(ws + 0);          // 16 int
  int*   work = (int*)(ws + 128);        // WMAX*2 int
  int*   woff = (int*)(ws + 1024);       // 16 int
  int*   list = (int*)(ws + 4096);       // 16*2048 int
  int*   rec  = (int*)(ws + 139264);     // 2048*4 int
  float* wrec = (float*)(ws + 172032);   // 2048*2 f32
  unsigned short* xbf = (unsigned short*)(ws + 1 * MB);    // 4 MB
  unsigned short* hid = (unsigned short*)(ws + 5 * MB);    // 16 MB
  unsigned short* op  = (unsigned short*)(ws + 21 * MB);   // 8 MB
  unsigned short* wmT = (unsigned short*)(ws + 32 * MB);   // 64 MB (reused by wdT)
  unsigned short* wfT = (unsigned short*)(ws + 96 * MB);   // 64 MB
  unsigned short* wdT = wmT;                               // alias: used after k_up

  hipMemsetAsync(cnt, 0, 64, stream);
  k_cvt_x<<<1024, 256, 0, stream>>>(x, xbf);
  k_router<<<TT, 256, 0, stream>>>(x, rw, rb, cnt, list, rec, wrec);
  k_sched<<<1, 64, 0, stream>>>(cnt, work, woff);
  k_trans<<<dim3(HH / 64, DD / 64, NE), 256, 0, stream>>>(bmag, wmT, DD, HH);
  k_trans<<<dim3(HH / 64, DD / 64, NE), 256, 0, stream>>>(bfreq, wfT, DD, HH);
  k_up<<<dim3(WMAX, HH / 64), 256, 0, stream>>>(xbf, wmT, wfT, bphase, cnt, list, work, woff, hid);
  k_trans<<<dim3(DD / 64, HH / 64, NE), 256, 0, stream>>>(bdown, wdT, HH, DD);
  k_down<<<dim3(WMAX, DD / 64), 256, 0, stream>>>(hid, wdT, cnt, work, woff, op);
  k_norm<<<TT, 256, 0, stream>>>(op, woff, rec, wrec, nw, out);
}